// Round 5
// baseline (377.994 us; speedup 1.0000x reference)
//
#include <hip/hip_runtime.h>
#include <math.h>

#define NTOK 49
#define KDIM 128
#define NH 4
#define HD 32
#define NW 64
#define QK_SCALE 0.17677669529663687f  // 32^-0.5
#define NBLK 512

typedef __attribute__((ext_vector_type(8))) short bf16x8;
typedef __attribute__((ext_vector_type(4))) float f32x4;
typedef __attribute__((ext_vector_type(8))) unsigned short us8;

static __device__ __forceinline__ unsigned short f2b(float f) {
    union { float f; unsigned int u; } v; v.f = f;
    return (unsigned short)((v.u + 0x7fffu + ((v.u >> 16) & 1u)) >> 16);  // RNE
}

// ---------------- workspace layout (bytes) ----------------
#define WS_WQ   0u            // qkv_w bf16 [384][128], Q rows pre-scaled    98304 B
#define WS_WP   98304u        // proj_w bf16 [128][128]                      32768 B
#define WS_FB2  131072u       // fb2 frag-ordered [64][4][4][4][64][4] f32 4194304 B
#define WS_REQ  (131072ull + 4194304ull)

// ---------- prep: weight cvt + fragment-ordered fused bias+mask table ----------
// grid 1216x256: blocks [0,192) weights, [192,1216) fb2.
__global__ void k_prep(const float* __restrict__ qkv_w, const float* __restrict__ proj_w,
                       const float* __restrict__ bias_table, const int* __restrict__ rel_index,
                       const float* __restrict__ attn_mask,
                       unsigned short* __restrict__ wq, unsigned short* __restrict__ wp,
                       float4* __restrict__ fb2) {
    const int bid = blockIdx.x, t = threadIdx.x;
    if (bid < 192) {
        int i = bid * 256 + t;                 // < 49152
        float v = qkv_w[i];
        if (i < KDIM * KDIM) v *= QK_SCALE;    // Q rows pre-scaled
        wq[i] = f2b(v);
        if (i < KDIM * KDIM) wp[i] = f2b(proj_w[i]);
    } else {
        int i2 = (bid - 192) * 256 + t;        // < 262144 float4s
        int lane = i2 & 63;
        int ct = (i2 >> 6) & 3;
        int mt = (i2 >> 8) & 3;
        int h  = (i2 >> 10) & 3;
        int wm = i2 >> 12;
        int fr = lane & 15, fg = lane >> 4;
        int k = ct * 16 + fr;
        float4 o;
        #pragma unroll
        for (int reg = 0; reg < 4; ++reg) {
            int q = mt * 16 + fg * 4 + reg;
            float val;
            if (k >= NTOK)      val = -1e30f;   // masked keys baked in
            else if (q >= NTOK) val = 0.f;      // pad queries: don't-care
            else val = bias_table[rel_index[q * NTOK + k] * NH + h]
                     + attn_mask[((size_t)wm * NTOK + q) * NTOK + k];
            ((float*)&o)[reg] = val;
        }
        fb2[i2] = o;
    }
}

// ---------------- persistent fused kernel: 512 blocks x (B/512) windows ----------------
// LDS 76800 B -> 2 blocks/CU (8 waves).  Overlays:
//   s_x [64][136]       : x tile (double-buffered via xpre registers)
//   s_q [4][64][40]     : Q   (s_p [4][64][72] overlays q+k after B2)
//   s_k [4][64][40]     : K
//   vt  [4][32][72]     : V^T (s_o [64][136] overlays after B3a)
__launch_bounds__(256, 2)
__global__ void k_fused(const float* __restrict__ x,
                        const unsigned short* __restrict__ wq,
                        const unsigned short* __restrict__ wp,
                        const float* __restrict__ qkv_b,
                        const float* __restrict__ proj_b,
                        const float4* __restrict__ fb2,
                        float* __restrict__ out,
                        int npb, int lastw) {
    __shared__ __align__(16) char arena[76800];
    unsigned short* s_x = (unsigned short*)arena;             // [64][136]
    unsigned short* s_q = (unsigned short*)(arena + 17408);   // [4][64][40]
    unsigned short* s_k = (unsigned short*)(arena + 37888);   // [4][64][40]
    unsigned short* s_p = (unsigned short*)(arena + 17408);   // [4][64][72]
    unsigned short* vt  = (unsigned short*)(arena + 58368);   // [4][32][72]
    unsigned short* s_o = (unsigned short*)(arena + 58368);   // [64][136]

    const int t = threadIdx.x;
    const int lane = t & 63, wid = t >> 6;
    const int fr = lane & 15, fg = lane >> 4;

    // ---- prologue: persistent qkv weight fragments + biases (L2 -> regs, once) ----
    bf16x8 bw[6][4]; float bq[6];
    #pragma unroll
    for (int i = 0; i < 6; ++i) {
        const int nt = wid * 6 + i;
        #pragma unroll
        for (int ks = 0; ks < 4; ++ks)
            bw[i][ks] = *(const bf16x8*)(wq + (nt * 16 + fr) * KDIM + ks * 32 + fg * 8);
        bq[i] = qkv_b[nt * 16 + fr] * ((nt >> 3) == 0 ? QK_SCALE : 1.f);
    }
    float pb[2];
    #pragma unroll
    for (int i = 0; i < 2; ++i) pb[i] = proj_b[(wid * 2 + i) * 16 + fr];

    // zero pad rows 49..63 of s_x (written once; never touched again)
    if (t < 255) {
        int row = 49 + t / 17, c8 = (t % 17) * 8;
        *(us8*)&s_x[row * 136 + c8] = (us8){0,0,0,0,0,0,0,0};
    }

    const int w0 = blockIdx.x * npb;
    float4 xpre[7];
    {   // prologue pipeline: x(w0) -> regs -> LDS ; x(w0+1) -> regs
        const float4* xg = (const float4*)(x + (size_t)w0 * NTOK * KDIM);
        #pragma unroll
        for (int k2 = 0; k2 < 7; ++k2) { int i = k2 * 256 + t; if (i < 1568) xpre[k2] = xg[i]; }
        #pragma unroll
        for (int k2 = 0; k2 < 7; ++k2) {
            int i = k2 * 256 + t;
            if (i < 1568) {
                int row = i >> 5, col = (i & 31) * 4;
                float4 v = xpre[k2];
                ushort4 pk = { f2b(v.x), f2b(v.y), f2b(v.z), f2b(v.w) };
                *(ushort4*)&s_x[row * 136 + col] = pk;
            }
        }
        int wn = (w0 + 1 <= lastw) ? w0 + 1 : lastw;
        const float4* xg2 = (const float4*)(x + (size_t)wn * NTOK * KDIM);
        #pragma unroll
        for (int k2 = 0; k2 < 7; ++k2) { int i = k2 * 256 + t; if (i < 1568) xpre[k2] = xg2[i]; }
    }
    __syncthreads();

    for (int j = 0; j < npb; ++j) {
        const int w = w0 + j;
        const int wm = w & (NW - 1);
        const size_t gb = (size_t)w * NTOK;

        // ---- phase 1a: A-fragments of x(w) ----
        bf16x8 ax[4][4];
        #pragma unroll
        for (int mt = 0; mt < 4; ++mt)
            #pragma unroll
            for (int ks = 0; ks < 4; ++ks)
                ax[mt][ks] = *(const bf16x8*)&s_x[(mt * 16 + fr) * 136 + ks * 32 + fg * 8];
        __syncthreads();   // BA: all s_x reads done

        // ---- phase 1b: s_x <- x(w+1) from prefetch regs ----
        #pragma unroll
        for (int k2 = 0; k2 < 7; ++k2) {
            int i = k2 * 256 + t;
            if (i < 1568) {
                int row = i >> 5, col = (i & 31) * 4;
                float4 v = xpre[k2];
                ushort4 pk = { f2b(v.x), f2b(v.y), f2b(v.z), f2b(v.w) };
                *(ushort4*)&s_x[row * 136 + col] = pk;
            }
        }

        // ---- phase 1c: qkv MFMAs (weights from registers) + epilogue ----
        #pragma unroll
        for (int i = 0; i < 6; ++i) {
            const int nt = wid * 6 + i;
            const int which = nt >> 3;            // 0=Q,1=K,2=V (wave-uniform)
            const int head = (nt >> 1) & 3;
            const int dbase = (nt & 1) * 16;
            f32x4 acc[4];
            #pragma unroll
            for (int mt = 0; mt < 4; ++mt) acc[mt] = (f32x4){0.f, 0.f, 0.f, 0.f};
            #pragma unroll
            for (int ks = 0; ks < 4; ++ks)
                #pragma unroll
                for (int mt = 0; mt < 4; ++mt)
                    acc[mt] = __builtin_amdgcn_mfma_f32_16x16x32_bf16(ax[mt][ks], bw[i][ks], acc[mt], 0, 0, 0);
            const float bias = bq[i];
            if (which == 2) {
                unsigned short* base = vt + head * (32 * 72) + (dbase + fr) * 72;
                #pragma unroll
                for (int mt = 0; mt < 4; ++mt) {
                    ushort4 pk = { f2b(acc[mt][0] + bias), f2b(acc[mt][1] + bias),
                                   f2b(acc[mt][2] + bias), f2b(acc[mt][3] + bias) };
                    *(ushort4*)&base[mt * 16 + fg * 4] = pk;
                }
            } else {
                unsigned short* base = (which == 0 ? s_q : s_k) + head * (64 * 40) + dbase + fr;
                #pragma unroll
                for (int mt = 0; mt < 4; ++mt)
                    #pragma unroll
                    for (int reg = 0; reg < 4; ++reg)
                        base[(mt * 16 + fg * 4 + reg) * 40] = f2b(acc[mt][reg] + bias);
            }
        }
        __syncthreads();   // B1: s_q/s_k/vt ready (and s_x write done)

        // ---- phase 2: S = Q K^T (wave = head), softmax in regs, fb coalesced ----
        f32x4 sacc[4][4];
        {
            const unsigned short* q_h = s_q + wid * (64 * 40);
            const unsigned short* k_h = s_k + wid * (64 * 40);
            bf16x8 aq[4];
            #pragma unroll
            for (int mt = 0; mt < 4; ++mt)
                aq[mt] = *(const bf16x8*)&q_h[(mt * 16 + fr) * 40 + fg * 8];
            #pragma unroll
            for (int ct = 0; ct < 4; ++ct) {
                bf16x8 bk = *(const bf16x8*)&k_h[(ct * 16 + fr) * 40 + fg * 8];
                #pragma unroll
                for (int mt = 0; mt < 4; ++mt)
                    sacc[mt][ct] = __builtin_amdgcn_mfma_f32_16x16x32_bf16(aq[mt], bk, (f32x4){0.f,0.f,0.f,0.f}, 0, 0, 0);
            }
            const float4* fbb = fb2 + ((size_t)((wm << 2) + wid) << 10);
            #pragma unroll
            for (int mt = 0; mt < 4; ++mt) {
                float4 fbm[4];
                #pragma unroll
                for (int ct = 0; ct < 4; ++ct) fbm[ct] = fbb[(mt * 4 + ct) * 64 + lane];
                #pragma unroll
                for (int reg = 0; reg < 4; ++reg) {
                    float v[4];
                    #pragma unroll
                    for (int ct = 0; ct < 4; ++ct)
                        v[ct] = sacc[mt][ct][reg] + ((const float*)&fbm[ct])[reg];
                    float m = fmaxf(fmaxf(v[0], v[1]), fmaxf(v[2], v[3]));
                    #pragma unroll
                    for (int sft = 1; sft < 16; sft <<= 1) m = fmaxf(m, __shfl_xor(m, sft));
                    float sum = 0.f;
                    #pragma unroll
                    for (int ct = 0; ct < 4; ++ct) { float e = __expf(v[ct] - m); v[ct] = e; sum += e; }
                    #pragma unroll
                    for (int sft = 1; sft < 16; sft <<= 1) sum += __shfl_xor(sum, sft);
                    const float r = 1.f / sum;
                    #pragma unroll
                    for (int ct = 0; ct < 4; ++ct) sacc[mt][ct][reg] = v[ct] * r;
                }
            }
        }
        __syncthreads();   // B2: all s_q/s_k reads done; P overlay safe

        // ---- phase 3: x(w+2) prefetch issue; P -> LDS; PV ----
        {
            int wn = (w + 2 <= lastw) ? w + 2 : lastw;
            const float4* xg = (const float4*)(x + (size_t)wn * NTOK * KDIM);
            #pragma unroll
            for (int k2 = 0; k2 < 7; ++k2) { int i = k2 * 256 + t; if (i < 1568) xpre[k2] = xg[i]; }
        }
        f32x4 oacc[4][2];
        {
            unsigned short* p_h = s_p + wid * (64 * 72);
            #pragma unroll
            for (int mt = 0; mt < 4; ++mt)
                #pragma unroll
                for (int ct = 0; ct < 4; ++ct)
                    #pragma unroll
                    for (int reg = 0; reg < 4; ++reg)
                        p_h[(mt * 16 + fg * 4 + reg) * 72 + ct * 16 + fr] = f2b(sacc[mt][ct][reg]);

            const unsigned short* vt_h = vt + wid * (32 * 72);
            bf16x8 bv[2][2];
            #pragma unroll
            for (int ni = 0; ni < 2; ++ni)
                #pragma unroll
                for (int ks = 0; ks < 2; ++ks)
                    bv[ni][ks] = *(const bf16x8*)&vt_h[(ni * 16 + fr) * 72 + ks * 32 + fg * 8];
            #pragma unroll
            for (int mt = 0; mt < 4; ++mt) {
                oacc[mt][0] = (f32x4){0.f,0.f,0.f,0.f};
                oacc[mt][1] = (f32x4){0.f,0.f,0.f,0.f};
                #pragma unroll
                for (int ks = 0; ks < 2; ++ks) {
                    bf16x8 ap = *(const bf16x8*)&p_h[(mt * 16 + fr) * 72 + ks * 32 + fg * 8];
                    #pragma unroll
                    for (int ni = 0; ni < 2; ++ni)
                        oacc[mt][ni] = __builtin_amdgcn_mfma_f32_16x16x32_bf16(ap, bv[ni][ks], oacc[mt][ni], 0, 0, 0);
                }
            }
        }
        __syncthreads();   // B3a: all vt/P reads done -> s_o overlay safe
        #pragma unroll
        for (int mt = 0; mt < 4; ++mt)
            #pragma unroll
            for (int ni = 0; ni < 2; ++ni)
                #pragma unroll
                for (int reg = 0; reg < 4; ++reg)
                    s_o[(mt * 16 + fg * 4 + reg) * 136 + wid * 32 + ni * 16 + fr] = f2b(oacc[mt][ni][reg]);
        __syncthreads();   // B3b: s_o ready

        // ---- phase 4: out = o @ proj_w^T + proj_b (proj frags from L2, per window) ----
        {
            bf16x8 ao[4][4];
            #pragma unroll
            for (int mt = 0; mt < 4; ++mt)
                #pragma unroll
                for (int ks = 0; ks < 4; ++ks)
                    ao[mt][ks] = *(const bf16x8*)&s_o[(mt * 16 + fr) * 136 + ks * 32 + fg * 8];
            #pragma unroll
            for (int i = 0; i < 2; ++i) {
                const int nt = wid * 2 + i;
                bf16x8 pw[4];
                #pragma unroll
                for (int ks = 0; ks < 4; ++ks)
                    pw[ks] = *(const bf16x8*)(wp + (nt * 16 + fr) * KDIM + ks * 32 + fg * 8);
                f32x4 acc[4];
                #pragma unroll
                for (int mt = 0; mt < 4; ++mt) acc[mt] = (f32x4){0.f,0.f,0.f,0.f};
                #pragma unroll
                for (int ks = 0; ks < 4; ++ks)
                    #pragma unroll
                    for (int mt = 0; mt < 4; ++mt)
                        acc[mt] = __builtin_amdgcn_mfma_f32_16x16x32_bf16(ao[mt][ks], pw[ks], acc[mt], 0, 0, 0);
                #pragma unroll
                for (int mt = 0; mt < 4; ++mt)
                    #pragma unroll
                    for (int reg = 0; reg < 4; ++reg) {
                        const int tok = mt * 16 + fg * 4 + reg;
                        if (tok < NTOK)
                            out[(gb + tok) * KDIM + nt * 16 + fr] = acc[mt][reg] + pb[i];
                    }
            }
        }
        __syncthreads();   // B4: s_o reads done before next window's vt writes
    }
}

// ---------- fallback (fp32, ws-independent) ----------
__launch_bounds__(256, 1)
__global__ void swin_window_attn_fallback(
    const float* __restrict__ x, const float* __restrict__ attn_mask,
    const float* __restrict__ qkv_w, const float* __restrict__ qkv_b,
    const float* __restrict__ proj_w, const float* __restrict__ proj_b,
    const float* __restrict__ bias_table, const int* __restrict__ rel_index,
    float* __restrict__ out)
{
    __shared__ float xs[NTOK * 129];
    __shared__ float wt[64 * 129];
    __shared__ float s_qt[NH * HD * NTOK];
    __shared__ float s_k[NH * NTOK * HD];
    __shared__ float s_v[NH * NTOK * HD];
    __shared__ float s_ot[KDIM * NTOK];
    const int b = blockIdx.x, tid = threadIdx.x, wm = b & 63;
    const float* xg = x + (size_t)b * (NTOK * KDIM);
    for (int i = tid; i < (NTOK * KDIM) / 4; i += 256) {
        float4 t = reinterpret_cast<const float4*>(xg)[i];
        int idx = i * 4; int row = idx >> 7, col = idx & 127;
        float* dst = &xs[row * 129 + col];
        dst[0]=t.x; dst[1]=t.y; dst[2]=t.z; dst[3]=t.w;
    }
    __syncthreads();
    const int cx = tid & 15, ny = tid >> 4;
    const float* xrow[4];
    #pragma unroll
    for (int a = 0; a < 4; ++a) { int n = ny + 16*a; xrow[a] = &xs[(n < NTOK ? n : NTOK-1) * 129]; }
    for (int ct = 0; ct < 6; ++ct) {
        const float4* wg = reinterpret_cast<const float4*>(qkv_w + ct * (64 * KDIM));
        for (int i = tid; i < (64 * KDIM) / 4; i += 256) {
            float4 t = wg[i]; int idx = i * 4; int row = idx >> 7, col = idx & 127;
            float* dst = &wt[row * 129 + col];
            dst[0]=t.x; dst[1]=t.y; dst[2]=t.z; dst[3]=t.w;
        }
        __syncthreads();
        float acc[4][4];
        #pragma unroll
        for (int a=0;a<4;++a) for (int j=0;j<4;++j) acc[a][j]=0.f;
        for (int k = 0; k < KDIM; ++k) {
            float xr[4], wr[4];
            #pragma unroll
            for (int a=0;a<4;++a) xr[a]=xrow[a][k];
            #pragma unroll
            for (int j=0;j<4;++j) wr[j]=wt[(cx*4+j)*129+k];
            #pragma unroll
            for (int a=0;a<4;++a) for (int j=0;j<4;++j) acc[a][j]+=xr[a]*wr[j];
        }
        #pragma unroll
        for (int j = 0; j < 4; ++j) {
            const int c = ct*64 + cx*4 + j, which = c>>7, h = (c>>5)&3, d = c&31;
            const float bv = qkv_b[c];
            #pragma unroll
            for (int a = 0; a < 4; ++a) {
                int n = ny + 16*a;
                if (n < NTOK) {
                    float val = acc[a][j] + bv;
                    if (which==0)      s_qt[(h*HD+d)*NTOK+n] = val*QK_SCALE;
                    else if (which==1) s_k[(h*NTOK+n)*HD+d] = val;
                    else               s_v[(h*NTOK+n)*HD+d] = val;
                }
            }
        }
        __syncthreads();
    }
    {
        const int h = tid >> 6, lane = tid & 63;
        const int r = lane < NTOK ? lane : NTOK-1;
        float qreg[HD];
        #pragma unroll
        for (int d=0;d<HD;++d) qreg[d]=s_qt[(h*HD+d)*NTOK+r];
        const int* ri = rel_index + r*NTOK;
        const float* mrow = attn_mask + ((size_t)wm*NTOK + r)*NTOK;
        float p[NTOK]; float mxv = -1e30f;
        #pragma unroll
        for (int j=0;j<NTOK;++j) {
            const float* krow = &s_k[(h*NTOK+j)*HD];
            float s=0.f;
            #pragma unroll
            for (int d=0;d<HD;++d) s += qreg[d]*krow[d];
            s += bias_table[ri[j]*NH+h] + mrow[j];
            p[j]=s; mxv=fmaxf(mxv,s);
        }
        float sum=0.f;
        #pragma unroll
        for (int j=0;j<NTOK;++j){ float e=__expf(p[j]-mxv); p[j]=e; sum+=e; }
        const float rsv = 1.0f/sum;
        float o[HD];
        #pragma unroll
        for (int d=0;d<HD;++d) o[d]=0.f;
        #pragma unroll
        for (int j=0;j<NTOK;++j){
            float pj=p[j]*rsv;
            const float* vrow=&s_v[(h*NTOK+j)*HD];
            #pragma unroll
            for (int d=0;d<HD;++d) o[d]+=pj*vrow[d];
        }
        if (lane < NTOK) {
            #pragma unroll
            for (int d=0;d<HD;++d) s_ot[(h*HD+d)*NTOK+r]=o[d];
        }
    }
    __syncthreads();
    float* outg = out + (size_t)b * (NTOK * KDIM);
    for (int ct = 0; ct < 2; ++ct) {
        const float4* wg = reinterpret_cast<const float4*>(proj_w + ct * (64 * KDIM));
        for (int i = tid; i < (64 * KDIM) / 4; i += 256) {
            float4 t = wg[i]; int idx = i * 4; int row = idx >> 7, col = idx & 127;
            float* dst = &wt[row * 129 + col];
            dst[0]=t.x; dst[1]=t.y; dst[2]=t.z; dst[3]=t.w;
        }
        __syncthreads();
        float acc[4][4];
        #pragma unroll
        for (int a=0;a<4;++a) for (int j=0;j<4;++j) acc[a][j]=0.f;
        int nclamp[4];
        #pragma unroll
        for (int a=0;a<4;++a){ int n=ny+16*a; nclamp[a]=(n<NTOK?n:NTOK-1); }
        for (int k = 0; k < KDIM; ++k) {
            float xr[4], wr[4];
            #pragma unroll
            for (int a=0;a<4;++a) xr[a]=s_ot[k*NTOK+nclamp[a]];
            #pragma unroll
            for (int j=0;j<4;++j) wr[j]=wt[(cx*4+j)*129+k];
            #pragma unroll
            for (int a=0;a<4;++a) for (int j=0;j<4;++j) acc[a][j]+=xr[a]*wr[j];
        }
        const int c0 = ct*64 + cx*4;
        float pbv[4];
        #pragma unroll
        for (int j=0;j<4;++j) pbv[j]=proj_b[c0+j];
        #pragma unroll
        for (int a = 0; a < 4; ++a) {
            int n = ny + 16*a;
            if (n < NTOK) {
                float4 res; res.x=acc[a][0]+pbv[0]; res.y=acc[a][1]+pbv[1];
                res.z=acc[a][2]+pbv[2]; res.w=acc[a][3]+pbv[3];
                *reinterpret_cast<float4*>(&outg[n*KDIM+c0]) = res;
            }
        }
        __syncthreads();
    }
}

extern "C" void kernel_launch(void* const* d_in, const int* in_sizes, int n_in,
                              void* d_out, int out_size, void* d_ws, size_t ws_size,
                              hipStream_t stream) {
    const float* x          = (const float*)d_in[0];
    const float* attn_mask  = (const float*)d_in[1];
    const float* qkv_w      = (const float*)d_in[2];
    const float* qkv_b      = (const float*)d_in[3];
    const float* proj_w     = (const float*)d_in[4];
    const float* proj_b     = (const float*)d_in[5];
    const float* bias_table = (const float*)d_in[6];
    const int*   rel_index  = (const int*)d_in[7];
    float* out = (float*)d_out;
    const int B = in_sizes[0] / (NTOK * KDIM);   // 4096

    if (ws_size >= WS_REQ && B >= NBLK && (B % NBLK) == 0) {
        unsigned short* wqp = (unsigned short*)((char*)d_ws + WS_WQ);
        unsigned short* wpp = (unsigned short*)((char*)d_ws + WS_WP);
        float4*         fbp = (float4*)((char*)d_ws + WS_FB2);

        k_prep<<<1216, 256, 0, stream>>>(qkv_w, proj_w, bias_table, rel_index, attn_mask,
                                         wqp, wpp, fbp);
        k_fused<<<NBLK, 256, 0, stream>>>(x, wqp, wpp, qkv_b, proj_b, fbp, out,
                                          B / NBLK, B - 1);
    } else {
        swin_window_attn_fallback<<<B, 256, 0, stream>>>(
            x, attn_mask, qkv_w, qkv_b, proj_w, proj_b, bias_table, rel_index, out);
    }
}

// Round 6
// 302.429 us; speedup vs baseline: 1.2499x; 1.2499x over previous
//
#include <hip/hip_runtime.h>
#include <math.h>

#define NTOK 49
#define KDIM 128
#define NH 4
#define HD 32
#define NW 64
#define QK_SCALE 0.17677669529663687f  // 32^-0.5

typedef __attribute__((ext_vector_type(8))) short bf16x8;
typedef __attribute__((ext_vector_type(4))) float f32x4;
typedef __attribute__((ext_vector_type(8))) unsigned short us8;

static __device__ __forceinline__ unsigned short f2b(float f) {
    union { float f; unsigned int u; } v; v.f = f;
    return (unsigned short)((v.u + 0x7fffu + ((v.u >> 16) & 1u)) >> 16);  // RNE
}

// ---------------- workspace layout (bytes) ----------------
#define WS_WQ   0u            // qkv_w bf16 [384][128], Q rows pre-scaled   98304 B
#define WS_WP   98304u        // proj_w bf16 [128][128]                     32768 B
#define WS_BS   131072u       // bias_sw float4 [h][kt][qt][lane]           65536 B (L2-resident)
#define WS_MB   196608u       // maskbits uint2 [wm][lane]                  32768 B (L2-resident)
#define WS_REQ  229376ull

// ---------- prep: weights bf16 + swapped-frag bias table + mask bitpack ----------
// grid 224: [0,192) weights, [192,208) bias_sw, [208,224) maskbits.
__global__ void k_prep(const float* __restrict__ qkv_w, const float* __restrict__ proj_w,
                       const float* __restrict__ bias_table, const int* __restrict__ rel_index,
                       const float* __restrict__ attn_mask,
                       unsigned short* __restrict__ wq, unsigned short* __restrict__ wp,
                       float4* __restrict__ bs, uint2* __restrict__ mb) {
    const int bid = blockIdx.x, t = threadIdx.x;
    if (bid < 192) {
        int i = bid * 256 + t;                 // < 49152
        float v = qkv_w[i];
        if (i < KDIM * KDIM) v *= QK_SCALE;    // Q rows pre-scaled
        wq[i] = f2b(v);
        if (i < KDIM * KDIM) wp[i] = f2b(proj_w[i]);
    } else if (bid < 208) {
        int i = (bid - 192) * 256 + t;         // < 4096 float4
        int lane = i & 63, qt = (i >> 6) & 3, kt = (i >> 8) & 3, h = i >> 10;
        int fr = lane & 15, fg = lane >> 4;
        int q = qt * 16 + fr;
        float4 o;
        #pragma unroll
        for (int reg = 0; reg < 4; ++reg) {
            int k = kt * 16 + fg * 4 + reg;
            float val;
            if (k >= NTOK)      val = -1e30f;                       // key mask baked in
            else if (q >= NTOK) val = 0.f;                          // pad query: don't-care
            else val = bias_table[rel_index[q * NTOK + k] * NH + h];
            ((float*)&o)[reg] = val;
        }
        bs[i] = o;
    } else {
        int i = (bid - 208) * 256 + t;         // < 4096 uint2
        int lane = i & 63, wm = i >> 6;
        int fr = lane & 15, fg = lane >> 4;
        unsigned int lo = 0, hi = 0;
        #pragma unroll
        for (int bi = 0; bi < 64; ++bi) {
            int kt = bi >> 4, qt = (bi >> 2) & 3, reg = bi & 3;
            int q = qt * 16 + fr, k = kt * 16 + fg * 4 + reg;
            unsigned int bit = 0;
            if (q < NTOK && k < NTOK && attn_mask[((size_t)wm * NTOK + q) * NTOK + k] != 0.f)
                bit = 1;
            if (bi < 32) lo |= bit << bi; else hi |= bit << (bi - 32);
        }
        mb[i] = make_uint2(lo, hi);
    }
}

// ---------------- fused per-window kernel (4096 blocks, 3 barriers) ----------------
// LDS arena 76800 B -> 2 blocks/CU. Overlays:
//   [0,17408)      s_x [64][136] bf16           (s_o overlays after B1)
//   [17408,58368)  s_qk: per head 10240 B = q[64][40] | k[64][40]
//                  (P [64][72] overlays own head's region after S-phase reads)
//   [58368,76800)  vt [4][32][72] bf16
__launch_bounds__(256, 2)
__global__ void k_fused(const float* __restrict__ x,
                        const unsigned short* __restrict__ wq,
                        const unsigned short* __restrict__ wp,
                        const float* __restrict__ qkv_b,
                        const float* __restrict__ proj_b,
                        const float4* __restrict__ bs,
                        const uint2* __restrict__ mb,
                        float* __restrict__ out) {
    __shared__ __align__(16) char arena[76800];
    unsigned short* s_x  = (unsigned short*)arena;             // [64][136]
    unsigned short* s_o  = (unsigned short*)arena;             // [64][136]
    unsigned short* s_qk = (unsigned short*)(arena + 17408);   // [4][ q:2560 | k:2560 ] ushorts
    unsigned short* vt   = (unsigned short*)(arena + 58368);   // [4][32][72]

    const int b = blockIdx.x, t = threadIdx.x;
    const int lane = t & 63, wid = t >> 6;
    const int fr = lane & 15, fg = lane >> 4;
    const int wm = b & (NW - 1);
    const size_t gb = (size_t)b * NTOK;

    // ---- phase 0: stage x -> bf16 LDS; zero pad rows 49..63 ----
    {
        const float4* xg = (const float4*)(x + gb * KDIM);
        for (int i = t; i < NTOK * 32; i += 256) {           // 1568 float4
            float4 v = xg[i];
            int row = i >> 5, col = (i & 31) * 4;
            ushort4 pk = { f2b(v.x), f2b(v.y), f2b(v.z), f2b(v.w) };
            *(ushort4*)&s_x[row * 136 + col] = pk;
        }
        if (t < 255) {                                        // 15 rows x 17 us8
            int row = 49 + t / 17, c8 = (t % 17) * 8;
            *(us8*)&s_x[row * 136 + c8] = (us8){0,0,0,0,0,0,0,0};
        }
    }
    __syncthreads();   // B0

    // ---- phase 1: qkv GEMM; wave wid computes channel tiles nt = wid*6..wid*6+5 ----
    {
        bf16x8 ax[4][4];
        #pragma unroll
        for (int mt = 0; mt < 4; ++mt)
            #pragma unroll
            for (int ks = 0; ks < 4; ++ks)
                ax[mt][ks] = *(const bf16x8*)&s_x[(mt * 16 + fr) * 136 + ks * 32 + fg * 8];

        #pragma unroll
        for (int i = 0; i < 6; ++i) {
            const int nt = wid * 6 + i;
            const int which = nt >> 3;            // 0=Q,1=K,2=V (wave-uniform)
            const int head = (nt >> 1) & 3;
            const int dbase = (nt & 1) * 16;
            bf16x8 bw[4];
            #pragma unroll
            for (int ks = 0; ks < 4; ++ks)
                bw[ks] = *(const bf16x8*)(wq + (nt * 16 + fr) * KDIM + ks * 32 + fg * 8);
            f32x4 acc[4];
            #pragma unroll
            for (int mt = 0; mt < 4; ++mt) acc[mt] = (f32x4){0.f, 0.f, 0.f, 0.f};
            #pragma unroll
            for (int ks = 0; ks < 4; ++ks)
                #pragma unroll
                for (int mt = 0; mt < 4; ++mt)
                    acc[mt] = __builtin_amdgcn_mfma_f32_16x16x32_bf16(ax[mt][ks], bw[ks], acc[mt], 0, 0, 0);
            const float bias = qkv_b[nt * 16 + fr] * (which == 0 ? QK_SCALE : 1.f);
            if (which == 2) {
                // V: 4 consecutive toks at fixed d -> packed write into vt[head][d][tok]
                unsigned short* base = vt + head * (32 * 72) + (dbase + fr) * 72;
                #pragma unroll
                for (int mt = 0; mt < 4; ++mt) {
                    ushort4 pk = { f2b(acc[mt][0] + bias), f2b(acc[mt][1] + bias),
                                   f2b(acc[mt][2] + bias), f2b(acc[mt][3] + bias) };
                    *(ushort4*)&base[mt * 16 + fg * 4] = pk;
                }
            } else {
                unsigned short* base = s_qk + head * 5120 + (which == 1 ? 2560 : 0) + dbase + fr;
                #pragma unroll
                for (int mt = 0; mt < 4; ++mt)
                    #pragma unroll
                    for (int reg = 0; reg < 4; ++reg)
                        base[(mt * 16 + fg * 4 + reg) * 40] = f2b(acc[mt][reg] + bias);
            }
        }
    }
    __syncthreads();   // B1: q/k/vt ready; s_x dead (ax consumed)

    // ---- phase 2: swapped S^T = K Q^T (wave = head), softmax, P, PV ----
    f32x4 oacc[4][2];
    {
        // early loads (L2-resident small tables), in flight under the MFMAs
        const float4* bb = bs + ((size_t)wid << 10);
        float4 brg[4][4];
        #pragma unroll
        for (int kt = 0; kt < 4; ++kt)
            #pragma unroll
            for (int qt = 0; qt < 4; ++qt)
                brg[kt][qt] = bb[((kt << 2) + qt) * 64 + lane];
        const uint2 mbv = mb[(wm << 6) + lane];

        unsigned short* q_h = s_qk + wid * 5120;
        unsigned short* k_h = q_h + 2560;

        bf16x8 bq4[4];
        #pragma unroll
        for (int qt = 0; qt < 4; ++qt)
            bq4[qt] = *(const bf16x8*)&q_h[(qt * 16 + fr) * 40 + fg * 8];

        f32x4 sacc[4][4];   // [kt][qt]; lane holds S[k=kt*16+fg*4+reg][q=qt*16+fr]
        #pragma unroll
        for (int kt = 0; kt < 4; ++kt) {
            bf16x8 ak = *(const bf16x8*)&k_h[(kt * 16 + fr) * 40 + fg * 8];
            #pragma unroll
            for (int qt = 0; qt < 4; ++qt)
                sacc[kt][qt] = __builtin_amdgcn_mfma_f32_16x16x32_bf16(ak, bq4[qt], (f32x4){0.f,0.f,0.f,0.f}, 0, 0, 0);
        }

        // softmax: per qt, reduce 16 in-lane + 2 shuffles (fg groups)
        #pragma unroll
        for (int qt = 0; qt < 4; ++qt) {
            float vv[4][4];
            float mx = -1e30f;
            #pragma unroll
            for (int kt = 0; kt < 4; ++kt)
                #pragma unroll
                for (int reg = 0; reg < 4; ++reg) {
                    const int bi = kt * 16 + qt * 4 + reg;
                    const unsigned int w = (bi < 32) ? mbv.x : mbv.y;
                    const float mk = ((w >> (bi & 31)) & 1u) ? -100.f : 0.f;
                    float s = sacc[kt][qt][reg] + ((const float*)&brg[kt][qt])[reg] + mk;
                    vv[kt][reg] = s;
                    mx = fmaxf(mx, s);
                }
            mx = fmaxf(mx, __shfl_xor(mx, 16));
            mx = fmaxf(mx, __shfl_xor(mx, 32));
            float sum = 0.f;
            #pragma unroll
            for (int kt = 0; kt < 4; ++kt)
                #pragma unroll
                for (int reg = 0; reg < 4; ++reg) {
                    float e = __expf(vv[kt][reg] - mx);
                    vv[kt][reg] = e;
                    sum += e;
                }
            sum += __shfl_xor(sum, 16);
            sum += __shfl_xor(sum, 32);
            const float r = 1.f / sum;
            #pragma unroll
            for (int kt = 0; kt < 4; ++kt)
                #pragma unroll
                for (int reg = 0; reg < 4; ++reg)
                    sacc[kt][qt][reg] = vv[kt][reg] * r;
        }

        // P -> own head's LDS region (overlays own q|k; no barrier needed)
        unsigned short* p_h = q_h;   // [64][72]
        #pragma unroll
        for (int qt = 0; qt < 4; ++qt)
            #pragma unroll
            for (int kt = 0; kt < 4; ++kt) {
                ushort4 pk = { f2b(sacc[kt][qt][0]), f2b(sacc[kt][qt][1]),
                               f2b(sacc[kt][qt][2]), f2b(sacc[kt][qt][3]) };
                *(ushort4*)&p_h[(qt * 16 + fr) * 72 + kt * 16 + fg * 4] = pk;
            }

        // PV: O = P V  (A rows q from p_h, B rows d from vt)
        const unsigned short* vt_h = vt + wid * (32 * 72);
        bf16x8 bv[2][2];
        #pragma unroll
        for (int ni = 0; ni < 2; ++ni)
            #pragma unroll
            for (int ks = 0; ks < 2; ++ks)
                bv[ni][ks] = *(const bf16x8*)&vt_h[(ni * 16 + fr) * 72 + ks * 32 + fg * 8];
        #pragma unroll
        for (int mt = 0; mt < 4; ++mt) {
            oacc[mt][0] = (f32x4){0.f,0.f,0.f,0.f};
            oacc[mt][1] = (f32x4){0.f,0.f,0.f,0.f};
            #pragma unroll
            for (int ks = 0; ks < 2; ++ks) {
                bf16x8 ap = *(const bf16x8*)&p_h[(mt * 16 + fr) * 72 + ks * 32 + fg * 8];
                #pragma unroll
                for (int ni = 0; ni < 2; ++ni)
                    oacc[mt][ni] = __builtin_amdgcn_mfma_f32_16x16x32_bf16(ap, bv[ni][ks], oacc[mt][ni], 0, 0, 0);
            }
        }
        // O -> s_o[tok][C] (overlays dead s_x region)
        #pragma unroll
        for (int mt = 0; mt < 4; ++mt)
            #pragma unroll
            for (int ni = 0; ni < 2; ++ni)
                #pragma unroll
                for (int reg = 0; reg < 4; ++reg)
                    s_o[(mt * 16 + fg * 4 + reg) * 136 + wid * 32 + ni * 16 + fr] = f2b(oacc[mt][ni][reg]);
    }
    __syncthreads();   // B3: s_o complete (all heads)

    // ---- phase 3: out = o @ proj_w^T + proj_b ----
    {
        bf16x8 ao[4][4];
        #pragma unroll
        for (int mt = 0; mt < 4; ++mt)
            #pragma unroll
            for (int ks = 0; ks < 4; ++ks)
                ao[mt][ks] = *(const bf16x8*)&s_o[(mt * 16 + fr) * 136 + ks * 32 + fg * 8];
        #pragma unroll
        for (int i = 0; i < 2; ++i) {
            const int nt = wid * 2 + i;
            bf16x8 pw[4];
            #pragma unroll
            for (int ks = 0; ks < 4; ++ks)
                pw[ks] = *(const bf16x8*)(wp + (nt * 16 + fr) * KDIM + ks * 32 + fg * 8);
            f32x4 acc[4];
            #pragma unroll
            for (int mt = 0; mt < 4; ++mt) acc[mt] = (f32x4){0.f,0.f,0.f,0.f};
            #pragma unroll
            for (int ks = 0; ks < 4; ++ks)
                #pragma unroll
                for (int mt = 0; mt < 4; ++mt)
                    acc[mt] = __builtin_amdgcn_mfma_f32_16x16x32_bf16(ao[mt][ks], pw[ks], acc[mt], 0, 0, 0);
            const float pbv = proj_b[nt * 16 + fr];
            #pragma unroll
            for (int mt = 0; mt < 4; ++mt)
                #pragma unroll
                for (int reg = 0; reg < 4; ++reg) {
                    const int tok = mt * 16 + fg * 4 + reg;
                    if (tok < NTOK)
                        out[(gb + tok) * KDIM + nt * 16 + fr] = acc[mt][reg] + pbv;
                }
        }
    }
}

// ---------- fallback (fp32, ws-independent) ----------
__launch_bounds__(256, 1)
__global__ void swin_window_attn_fallback(
    const float* __restrict__ x, const float* __restrict__ attn_mask,
    const float* __restrict__ qkv_w, const float* __restrict__ qkv_b,
    const float* __restrict__ proj_w, const float* __restrict__ proj_b,
    const float* __restrict__ bias_table, const int* __restrict__ rel_index,
    float* __restrict__ out)
{
    __shared__ float xs[NTOK * 129];
    __shared__ float wt[64 * 129];
    __shared__ float s_qt[NH * HD * NTOK];
    __shared__ float s_k[NH * NTOK * HD];
    __shared__ float s_v[NH * NTOK * HD];
    __shared__ float s_ot[KDIM * NTOK];
    const int b = blockIdx.x, tid = threadIdx.x, wm = b & 63;
    const float* xg = x + (size_t)b * (NTOK * KDIM);
    for (int i = tid; i < (NTOK * KDIM) / 4; i += 256) {
        float4 t = reinterpret_cast<const float4*>(xg)[i];
        int idx = i * 4; int row = idx >> 7, col = idx & 127;
        float* dst = &xs[row * 129 + col];
        dst[0]=t.x; dst[1]=t.y; dst[2]=t.z; dst[3]=t.w;
    }
    __syncthreads();
    const int cx = tid & 15, ny = tid >> 4;
    const float* xrow[4];
    #pragma unroll
    for (int a = 0; a < 4; ++a) { int n = ny + 16*a; xrow[a] = &xs[(n < NTOK ? n : NTOK-1) * 129]; }
    for (int ct = 0; ct < 6; ++ct) {
        const float4* wg = reinterpret_cast<const float4*>(qkv_w + ct * (64 * KDIM));
        for (int i = tid; i < (64 * KDIM) / 4; i += 256) {
            float4 t = wg[i]; int idx = i * 4; int row = idx >> 7, col = idx & 127;
            float* dst = &wt[row * 129 + col];
            dst[0]=t.x; dst[1]=t.y; dst[2]=t.z; dst[3]=t.w;
        }
        __syncthreads();
        float acc[4][4];
        #pragma unroll
        for (int a=0;a<4;++a) for (int j=0;j<4;++j) acc[a][j]=0.f;
        for (int k = 0; k < KDIM; ++k) {
            float xr[4], wr[4];
            #pragma unroll
            for (int a=0;a<4;++a) xr[a]=xrow[a][k];
            #pragma unroll
            for (int j=0;j<4;++j) wr[j]=wt[(cx*4+j)*129+k];
            #pragma unroll
            for (int a=0;a<4;++a) for (int j=0;j<4;++j) acc[a][j]+=xr[a]*wr[j];
        }
        #pragma unroll
        for (int j = 0; j < 4; ++j) {
            const int c = ct*64 + cx*4 + j, which = c>>7, h = (c>>5)&3, d = c&31;
            const float bv = qkv_b[c];
            #pragma unroll
            for (int a = 0; a < 4; ++a) {
                int n = ny + 16*a;
                if (n < NTOK) {
                    float val = acc[a][j] + bv;
                    if (which==0)      s_qt[(h*HD+d)*NTOK+n] = val*QK_SCALE;
                    else if (which==1) s_k[(h*NTOK+n)*HD+d] = val;
                    else               s_v[(h*NTOK+n)*HD+d] = val;
                }
            }
        }
        __syncthreads();
    }
    {
        const int h = tid >> 6, lane = tid & 63;
        const int r = lane < NTOK ? lane : NTOK-1;
        float qreg[HD];
        #pragma unroll
        for (int d=0;d<HD;++d) qreg[d]=s_qt[(h*HD+d)*NTOK+r];
        const int* ri = rel_index + r*NTOK;
        const float* mrow = attn_mask + ((size_t)wm*NTOK + r)*NTOK;
        float p[NTOK]; float mxv = -1e30f;
        #pragma unroll
        for (int j=0;j<NTOK;++j) {
            const float* krow = &s_k[(h*NTOK+j)*HD];
            float s=0.f;
            #pragma unroll
            for (int d=0;d<HD;++d) s += qreg[d]*krow[d];
            s += bias_table[ri[j]*NH+h] + mrow[j];
            p[j]=s; mxv=fmaxf(mxv,s);
        }
        float sum=0.f;
        #pragma unroll
        for (int j=0;j<NTOK;++j){ float e=__expf(p[j]-mxv); p[j]=e; sum+=e; }
        const float rsv = 1.0f/sum;
        float o[HD];
        #pragma unroll
        for (int d=0;d<HD;++d) o[d]=0.f;
        #pragma unroll
        for (int j=0;j<NTOK;++j){
            float pj=p[j]*rsv;
            const float* vrow=&s_v[(h*NTOK+j)*HD];
            #pragma unroll
            for (int d=0;d<HD;++d) o[d]+=pj*vrow[d];
        }
        if (lane < NTOK) {
            #pragma unroll
            for (int d=0;d<HD;++d) s_ot[(h*HD+d)*NTOK+r]=o[d];
        }
    }
    __syncthreads();
    float* outg = out + (size_t)b * (NTOK * KDIM);
    for (int ct = 0; ct < 2; ++ct) {
        const float4* wg = reinterpret_cast<const float4*>(proj_w + ct * (64 * KDIM));
        for (int i = tid; i < (64 * KDIM) / 4; i += 256) {
            float4 t = wg[i]; int idx = i * 4; int row = idx >> 7, col = idx & 127;
            float* dst = &wt[row * 129 + col];
            dst[0]=t.x; dst[1]=t.y; dst[2]=t.z; dst[3]=t.w;
        }
        __syncthreads();
        float acc[4][4];
        #pragma unroll
        for (int a=0;a<4;++a) for (int j=0;j<4;++j) acc[a][j]=0.f;
        int nclamp[4];
        #pragma unroll
        for (int a=0;a<4;++a){ int n=ny+16*a; nclamp[a]=(n<NTOK?n:NTOK-1); }
        for (int k = 0; k < KDIM; ++k) {
            float xr[4], wr[4];
            #pragma unroll
            for (int a=0;a<4;++a) xr[a]=s_ot[k*NTOK+nclamp[a]];
            #pragma unroll
            for (int j=0;j<4;++j) wr[j]=wt[(cx*4+j)*129+k];
            #pragma unroll
            for (int a=0;a<4;++a) for (int j=0;j<4;++j) acc[a][j]+=xr[a]*wr[j];
        }
        const int c0 = ct*64 + cx*4;
        float pbv[4];
        #pragma unroll
        for (int j=0;j<4;++j) pbv[j]=proj_b[c0+j];
        #pragma unroll
        for (int a = 0; a < 4; ++a) {
            int n = ny + 16*a;
            if (n < NTOK) {
                float4 res; res.x=acc[a][0]+pbv[0]; res.y=acc[a][1]+pbv[1];
                res.z=acc[a][2]+pbv[2]; res.w=acc[a][3]+pbv[3];
                *reinterpret_cast<float4*>(&outg[n*KDIM+c0]) = res;
            }
        }
        __syncthreads();
    }
}

extern "C" void kernel_launch(void* const* d_in, const int* in_sizes, int n_in,
                              void* d_out, int out_size, void* d_ws, size_t ws_size,
                              hipStream_t stream) {
    const float* x          = (const float*)d_in[0];
    const float* attn_mask  = (const float*)d_in[1];
    const float* qkv_w      = (const float*)d_in[2];
    const float* qkv_b      = (const float*)d_in[3];
    const float* proj_w     = (const float*)d_in[4];
    const float* proj_b     = (const float*)d_in[5];
    const float* bias_table = (const float*)d_in[6];
    const int*   rel_index  = (const int*)d_in[7];
    float* out = (float*)d_out;
    const int B = in_sizes[0] / (NTOK * KDIM);   // 4096

    if (ws_size >= WS_REQ) {
        unsigned short* wqp = (unsigned short*)((char*)d_ws + WS_WQ);
        unsigned short* wpp = (unsigned short*)((char*)d_ws + WS_WP);
        float4*         bsp = (float4*)((char*)d_ws + WS_BS);
        uint2*          mbp = (uint2*)((char*)d_ws + WS_MB);

        k_prep<<<224, 256, 0, stream>>>(qkv_w, proj_w, bias_table, rel_index, attn_mask,
                                        wqp, wpp, bsp, mbp);
        k_fused<<<B, 256, 0, stream>>>(x, wqp, wpp, qkv_b, proj_b, bsp, mbp, out);
    } else {
        swin_window_attn_fallback<<<B, 256, 0, stream>>>(
            x, attn_mask, qkv_w, qkv_b, proj_w, proj_b, bias_table, rel_index, out);
    }
}